// Round 1
// 424.807 us; speedup vs baseline: 1.1057x; 1.1057x over previous
//
#include <hip/hip_runtime.h>
#include <hip/hip_bf16.h>

typedef short bf16x8 __attribute__((ext_vector_type(8)));
typedef float f32x4 __attribute__((ext_vector_type(4)));

#define HID 256
#define IN_DIM 128
#define M_BLOCK 64

__device__ __forceinline__ float bf2f(unsigned short x) {
    union { unsigned int u; float f; } c; c.u = ((unsigned int)x) << 16; return c.f;
}
__device__ __forceinline__ unsigned short f2bf(float f) {
    union { float f; unsigned int u; } c; c.f = f;
    unsigned int u = c.u;
    u += 0x7FFFu + ((u >> 16) & 1u);   // RNE
    return (unsigned short)(u >> 16);
}
__device__ __forceinline__ unsigned int pack2(float lo, float hi) {
    return (unsigned int)f2bf(lo) | ((unsigned int)f2bf(hi) << 16);
}

// Async global->LDS, 16B per lane. LDS dest is wave-uniform base + lane*16 (m104).
__device__ __forceinline__ void gload_lds16(const void* g, void* l) {
    __builtin_amdgcn_global_load_lds(
        (const __attribute__((address_space(1))) void*)g,
        (__attribute__((address_space(3))) void*)l,
        16, 0, 0);
}

// Runtime dtype guards (validated earlier: all float tensors fp32, indices int32).
__device__ __forceinline__ bool detect_bf16(const unsigned short* p, int strideElems) {
    const int lane = threadIdx.x & 63;
    unsigned int u = p[(size_t)2 * lane * strideElems];
    unsigned int e = (u >> 7) & 0xFFu;
    bool bad = ((u & 0x7FFFu) != 0u) && (e < 90u || e > 141u);
    return __ballot(bad) == 0ull;
}
__device__ __forceinline__ bool detect_idx64(const int* p) {
    const int lane = threadIdx.x & 63;
    int v = p[2 * (lane * 64) + 1];
    return __ballot(v != 0) == 0ull;
}

// ---- Table pre-conversion: fp32 (or bf16 passthrough) -> bf16 workspace tables ----
extern "C" __global__ void cvt_tables_kernel(
    const void* __restrict__ user_embed, const void* __restrict__ item_embed,
    unsigned short* __restrict__ uT, unsigned short* __restrict__ iT,
    long long nU8, long long nI8)
{
    const int t = blockIdx.y;
    const void* src = t ? item_embed : user_embed;
    unsigned short* dst = t ? iT : uT;
    const long long n8 = t ? nI8 : nU8;
    const bool bf = detect_bf16((const unsigned short*)src, 1024);
    long long i = (long long)blockIdx.x * 256 + threadIdx.x;
    const long long stride = (long long)gridDim.x * 256;
    if (bf) {
        const uint4* s = (const uint4*)src;
        for (; i < n8; i += stride)
            *reinterpret_cast<uint4*>(dst + i * 8) = s[i];
    } else {
        const float4* s = (const float4*)src;
        for (; i < n8; i += stride) {
            float4 f0 = s[2 * i];
            float4 f1 = s[2 * i + 1];
            uint4 o;
            o.x = pack2(f0.x, f0.y);
            o.y = pack2(f0.z, f0.w);
            o.z = pack2(f1.x, f1.y);
            o.w = pack2(f1.z, f1.w);
            *reinterpret_cast<uint4*>(dst + i * 8) = o;
        }
    }
}

// Pack W1 [256 k][256 n] row-major (fp32 or bf16) into bf16 B-fragment order:
// packed[kt][nt][lane][j] = bf16(W1[kt*32 + (lane>>4)*8 + j][nt*16 + (lane&15)])
extern "C" __global__ void pack_w1_kernel(
    const void* __restrict__ W1c,
    const void* __restrict__ W1b,
    unsigned short* __restrict__ outp)
{
    const int t = blockIdx.y;
    const void* W1 = t ? W1b : W1c;
    const unsigned short* W1u = (const unsigned short*)W1;
    const float* W1f = (const float*)W1;
    const bool w1bf = detect_bf16(W1u, 512);

    const int tid = blockIdx.x * 256 + threadIdx.x;   // 0..8191
    const int lane = tid & 63;
    const int nt = (tid >> 6) & 15;
    const int kt = tid >> 10;
    const int k0 = kt * 32 + (lane >> 4) * 8;
    const int n  = nt * 16 + (lane & 15);
    unsigned short vals[8];
#pragma unroll
    for (int j = 0; j < 8; ++j) {
        const int src = (k0 + j) * HID + n;
        vals[j] = w1bf ? W1u[src] : f2bf(W1f[src]);
    }
    unsigned short* dst = outp + (size_t)t * 65536 + (size_t)tid * 8;
    *reinterpret_cast<uint4*>(dst) = *reinterpret_cast<const uint4*>(vals);
}

extern "C" __global__ __launch_bounds__(256, 4)
void edge_mlp_kernel(
    const void* __restrict__ user_embed,
    const void* __restrict__ item_embed,
    const unsigned short* __restrict__ uT,   // bf16 ws tables (valid iff useWs)
    const unsigned short* __restrict__ iT,
    const int* __restrict__ u0, const int* __restrict__ v0,
    const int* __restrict__ u1, const int* __restrict__ v1,
    const unsigned short* __restrict__ packedW1,
    const void* __restrict__ b1_0, const void* __restrict__ w2_0,
    const void* __restrict__ b2_0,
    const void* __restrict__ b1_1, const void* __restrict__ w2_1,
    const void* __restrict__ b2_1,
    float* __restrict__ out, int E, int useWs)
{
    // LDS A-tile layout: [kchunk 0..31][edge 0..63][8 bf16] -> 32 KB, no padding.
    // kchunk = k/8 of the 256-wide concat row (0-15 user half, 16-31 item half).
    __shared__ __attribute__((aligned(16))) unsigned short sA[32 * 64 * 8];
    __shared__ float pRed[4][M_BLOCK];

    const int t  = blockIdx.y;
    const int e0 = blockIdx.x * M_BLOCK;
    const int tid = threadIdx.x;
    const int lane = tid & 63;
    const int wv = tid >> 6;

    const int* uI = t ? u1 : u0;
    const int* vI = t ? v1 : v0;
    const void* b1 = t ? b1_1 : b1_0;
    const void* w2 = t ? w2_1 : w2_0;
    const void* b2 = t ? b2_1 : b2_0;
    const unsigned short* pW = packedW1 + (size_t)t * 65536;

    const bool w2Bf = detect_bf16((const unsigned short*)w2, 2);

    // ---- gather: lane = edge, wave wv owns 8 k-chunks (wv<2: user half, else item) ----
    {
        const int* gI = (wv < 2) ? uI : vI;
        const bool g64 = detect_idx64(gI);
        const int e = e0 + lane;
        const int eC = (e < E) ? e : (E - 1);
        const size_t idx = (size_t)(g64 ? gI[2 * eC] : gI[eC]);

        if (useWs) {
            const unsigned short* tab = (wv < 2) ? uT : iT;
            const unsigned short* rowbase = tab + idx * IN_DIM + (wv & 1) * 64;
            unsigned short* sbase = &sA[(wv * 8) * 512];   // wave-uniform
#pragma unroll
            for (int c = 0; c < 8; ++c)
                gload_lds16(rowbase + c * 8, sbase + c * 512);
        } else {
            const void* tab = (wv < 2) ? user_embed : item_embed;
            const bool tbf = detect_bf16((const unsigned short*)tab, 1024);
            if (tbf) {
                const unsigned short* rowbase =
                    (const unsigned short*)tab + idx * IN_DIM + (wv & 1) * 64;
                unsigned short* sbase = &sA[(wv * 8) * 512];
#pragma unroll
                for (int c = 0; c < 8; ++c)
                    gload_lds16(rowbase + c * 8, sbase + c * 512);
            } else {
                const float* rowbase =
                    (const float*)tab + idx * IN_DIM + (wv & 1) * 64;
#pragma unroll
                for (int c = 0; c < 8; ++c) {
                    float4 f0 = *reinterpret_cast<const float4*>(rowbase + c * 8);
                    float4 f1 = *reinterpret_cast<const float4*>(rowbase + c * 8 + 4);
                    uint4 o;
                    o.x = pack2(f0.x, f0.y);
                    o.y = pack2(f0.z, f0.w);
                    o.z = pack2(f1.x, f1.y);
                    o.w = pack2(f1.z, f1.w);
                    // edge-major lane mapping: adjacent lanes -> adjacent 16B slots
                    *reinterpret_cast<uint4*>(&sA[((wv * 8 + c) * 64 + lane) * 8]) = o;
                }
            }
        }
    }
    __syncthreads();

    const int lq = lane >> 4;
    const int lm = lane & 15;

    f32x4 acc[4][4];
#pragma unroll
    for (int ms = 0; ms < 4; ++ms)
#pragma unroll
        for (int ntg = 0; ntg < 4; ++ntg)
            acc[ms][ntg] = (f32x4){0.f, 0.f, 0.f, 0.f};

#pragma unroll
    for (int kt = 0; kt < 8; ++kt) {
        bf16x8 aF[4];
#pragma unroll
        for (int ms = 0; ms < 4; ++ms)
            aF[ms] = *reinterpret_cast<const bf16x8*>(
                &sA[(((kt * 4 + lq) * 64) + ms * 16 + lm) * 8]);
#pragma unroll
        for (int ntg = 0; ntg < 4; ++ntg) {
            const int nt = wv * 4 + ntg;
            bf16x8 bF = *reinterpret_cast<const bf16x8*>(
                pW + (((size_t)(kt * 16 + nt) * 64 + lane) * 8));
#pragma unroll
            for (int ms = 0; ms < 4; ++ms)
                acc[ms][ntg] = __builtin_amdgcn_mfma_f32_16x16x32_bf16(
                    aF[ms], bF, acc[ms][ntg], 0, 0, 0);
        }
    }

    // ---- fused epilogue (fp32): relu(acc + b1) . w2, shuffle-reduce ----
    float part[4][4];
#pragma unroll
    for (int ms = 0; ms < 4; ++ms)
#pragma unroll
        for (int r = 0; r < 4; ++r) part[ms][r] = 0.f;

#pragma unroll
    for (int ntg = 0; ntg < 4; ++ntg) {
        const int n = (wv * 4 + ntg) * 16 + lm;
        const float b1n = w2Bf ? bf2f(((const unsigned short*)b1)[n]) : ((const float*)b1)[n];
        const float w2n = w2Bf ? bf2f(((const unsigned short*)w2)[n]) : ((const float*)w2)[n];
#pragma unroll
        for (int ms = 0; ms < 4; ++ms)
#pragma unroll
            for (int r = 0; r < 4; ++r) {
                float h = acc[ms][ntg][r] + b1n;
                h = fmaxf(h, 0.f);
                part[ms][r] = fmaf(h, w2n, part[ms][r]);
            }
    }

#pragma unroll
    for (int off = 1; off < 16; off <<= 1) {
#pragma unroll
        for (int ms = 0; ms < 4; ++ms)
#pragma unroll
            for (int r = 0; r < 4; ++r)
                part[ms][r] += __shfl_xor(part[ms][r], off, 64);
    }

    if (lm == 0) {
#pragma unroll
        for (int ms = 0; ms < 4; ++ms)
#pragma unroll
            for (int r = 0; r < 4; ++r)
                pRed[wv][ms * 16 + lq * 4 + r] = part[ms][r];
    }
    __syncthreads();

    if (tid < M_BLOCK) {
        const int e = e0 + tid;
        if (e < E) {
            const float b2v = w2Bf ? bf2f(((const unsigned short*)b2)[0]) : ((const float*)b2)[0];
            float s = b2v + pRed[0][tid] + pRed[1][tid] + pRed[2][tid] + pRed[3][tid];
            out[(size_t)t * E + e] = s;      // fp32 store
        }
    }
}

extern "C" void kernel_launch(void* const* d_in, const int* in_sizes, int n_in,
                              void* d_out, int out_size, void* d_ws, size_t ws_size,
                              hipStream_t stream)
{
    const void* user_embed = d_in[0];
    const void* item_embed = d_in[1];
    const int* u0 = (const int*)d_in[2];
    const int* v0 = (const int*)d_in[3];
    const int* u1 = (const int*)d_in[4];
    const int* v1 = (const int*)d_in[5];
    const void* W1c = d_in[6];
    const void* b1c = d_in[7];
    const void* w2c = d_in[8];
    const void* b2c = d_in[9];
    const void* W1b = d_in[10];
    const void* b1b = d_in[11];
    const void* w2b = d_in[12];
    const void* b2b = d_in[13];

    const int E = in_sizes[2];
    const size_t U = (size_t)in_sizes[0] / IN_DIM;   // user rows (in_sizes = element counts)
    const size_t I = (size_t)in_sizes[1] / IN_DIM;   // item rows

    unsigned short* packedW1 = (unsigned short*)d_ws;              // 256 KB
    unsigned short* uT = (unsigned short*)((char*)d_ws + 262144);  // bf16 user table
    unsigned short* iT = uT + U * IN_DIM;                          // bf16 item table
    const size_t need = 262144 + (U + I) * IN_DIM * sizeof(unsigned short);
    const int useWs = (ws_size >= need) ? 1 : 0;

    if (useWs) {
        const long long nU8 = (long long)U * IN_DIM / 8;
        const long long nI8 = (long long)I * IN_DIM / 8;
        hipLaunchKernelGGL(cvt_tables_kernel, dim3(4096, 2), dim3(256), 0, stream,
                           user_embed, item_embed, uT, iT, nU8, nI8);
    }

    hipLaunchKernelGGL(pack_w1_kernel, dim3(32, 2), dim3(256), 0, stream, W1c, W1b, packedW1);

    dim3 grid((E + M_BLOCK - 1) / M_BLOCK, 2);
    hipLaunchKernelGGL(edge_mlp_kernel, grid, dim3(256), 0, stream,
                       user_embed, item_embed, uT, iT, u0, v0, u1, v1, packedW1,
                       b1c, w2c, b2c, b1b, w2b, b2b,
                       (float*)d_out, E, useWs);
}